// Round 4
// baseline (411.329 us; speedup 1.0000x reference)
//
#include <hip/hip_runtime.h>

#define N_    8192
#define FIN_  256
#define NHID_ 128
#define E_    524288
#define KTOP  32
#define CAP   160   // bucket capacity per row; Binomial(E,1/N): mean 64, sigma 8 -> 160 = +12 sigma

// adj zero-fill split: gemm zeroes the first quarter, scatter the rest.
#define ADJ_Q4   (N_ * (size_t)N_ / 4)      // total float4 count = 16,777,216
#define GEMM_Z4  (ADJ_Q4 / 4)               // 4,194,304 float4  (16 per thread, 1024x256)
#define SCAT_Z4  (ADJ_Q4 - GEMM_Z4)         // 12,582,912 float4 (24 per thread, 2048x256)

// ---- fused: h = relu(x @ W1 + b1); a = h.We1; b = h.We2; cnt = 0; zero 1/4 of adj ----
__global__ __launch_bounds__(256) void k_gemm_ab(const float* __restrict__ x,
                                                 const float* __restrict__ W1,
                                                 const float* __restrict__ b1,
                                                 const float* __restrict__ We,
                                                 float* __restrict__ h,
                                                 float* __restrict__ a,
                                                 float* __restrict__ b,
                                                 int* __restrict__ cnt,
                                                 float* __restrict__ adj) {
    __shared__ float xs[8][FIN_];
    int t = threadIdx.x;
    int row0 = blockIdx.x * 8;
    const float4* xg = (const float4*)(x + (size_t)row0 * FIN_);
    float4* xs4 = (float4*)&xs[0][0];
    xs4[t]       = xg[t];          // 8*256 floats = 512 float4, 2 per thread
    xs4[t + 256] = xg[t + 256];
    if (t < 8) cnt[row0 + t] = 0;  // fused cnt zeroing (k_scatter is stream-ordered after)

    // fused zero-fill of adj's first quarter (write pipe is otherwise idle here)
    {
        float4* adj4 = (float4*)adj;
        float4 z4 = make_float4(0.f, 0.f, 0.f, 0.f);
        int tid = blockIdx.x * 256 + t;
#pragma unroll
        for (int i = 0; i < 16; ++i) adj4[(size_t)i * 262144 + tid] = z4;
    }
    __syncthreads();

    int row = t >> 5;
    int jg  = t & 31;
    const float* wp = W1 + jg * 4;
    float4 acc = *(const float4*)(b1 + jg * 4);
    const float* xr = xs[row];
#pragma unroll 8
    for (int k = 0; k < FIN_; ++k) {
        float4 w = *(const float4*)(wp + (size_t)k * NHID_);
        float xv = xr[k];
        acc.x = fmaf(xv, w.x, acc.x);
        acc.y = fmaf(xv, w.y, acc.y);
        acc.z = fmaf(xv, w.z, acc.z);
        acc.w = fmaf(xv, w.w, acc.w);
    }
    acc.x = fmaxf(acc.x, 0.f);
    acc.y = fmaxf(acc.y, 0.f);
    acc.z = fmaxf(acc.z, 0.f);
    acc.w = fmaxf(acc.w, 0.f);
    *(float4*)(h + (size_t)(row0 + row) * NHID_ + jg * 4) = acc;

    // epilogue: per-node scalars from the relu'd registers (32-lane tree per row)
    float4 we1 = *(const float4*)(We + jg * 4);
    float4 we2 = *(const float4*)(We + NHID_ + jg * 4);
    float p = acc.x * we1.x + acc.y * we1.y + acc.z * we1.z + acc.w * we1.w;
    float q = acc.x * we2.x + acc.y * we2.y + acc.z * we2.z + acc.w * we2.w;
#pragma unroll
    for (int o = 16; o > 0; o >>= 1) {
        p += __shfl_down(p, o, 32);
        q += __shfl_down(q, o, 32);
    }
    if (jg == 0) { a[row0 + row] = p; b[row0 + row] = q; }
}

// ---- bucket edges by row (atomic append) + zero remaining 3/4 of adj ----
__global__ __launch_bounds__(256) void k_scatter(const int* __restrict__ ei,
                                                 int* __restrict__ cnt,
                                                 int* __restrict__ ecol,
                                                 float* __restrict__ adj) {
    int e = blockIdx.x * 256 + threadIdx.x;
    int r = ei[e];
    int c = ei[E_ + e];
    int pos = atomicAdd(&cnt[r], 1);
    if (pos < CAP) ecol[r * CAP + pos] = c;

    // fused zero-fill of adj's remaining 3/4 (overlaps the atomic-latency chain)
    float4* adj4 = (float4*)adj + GEMM_Z4;
    float4 z4 = make_float4(0.f, 0.f, 0.f, 0.f);
#pragma unroll
    for (int i = 0; i < 24; ++i) adj4[(size_t)i * 524288 + e] = z4;
}

// ---- per-row sparsemax + topK threshold; writes ONLY the kept entries ----
// one wave per row; adj is already zeroed by the two kernels above.
__global__ __launch_bounds__(64) void k_rows(const int* __restrict__ cnt,
                                             const int* __restrict__ ecol,
                                             const float* __restrict__ a,
                                             const float* __restrict__ b,
                                             const float* __restrict__ be,
                                             float* __restrict__ adj) {
    __shared__ float zs[CAP];
    __shared__ int   cols[CAP];
    __shared__ float srt[CAP];
    __shared__ unsigned char dupf[CAP];
    __shared__ float s_tau, s_thresh;

    int r = blockIdx.x;
    int t = threadIdx.x;
    int m = cnt[r];
    if (m > CAP) m = CAP;
    if (m == 0) return;               // row stays all-zero

    // load bucket; z = a[r] + b[c] + be  (b[] is 32 KB, L2-resident gather)
    float ab = a[r] + be[0];
    for (int i = t; i < m; i += 64) {
        int c = ecol[r * CAP + i];
        cols[i] = c;
        zs[i] = ab + b[c];
    }
    __syncthreads();

    // phase 1: descending rank over ALL entries (dups included, like the reference)
    for (int i = t; i < m; i += 64) {
        float zi = zs[i];
        int ci = cols[i];
        int rank = 0;
        for (int jj = 0; jj < m; ++jj) {
            float zj = zs[jj];
            rank += (zj > zi) || (zj == zi && jj < i);
        }
        bool dup = false;
        for (int jj = 0; jj < i; ++jj)
            if (cols[jj] == ci) { dup = true; break; }
        srt[rank] = zi;
        dupf[i] = dup ? 1 : 0;
    }
    __syncthreads();

    // phase 2: sparsemax support size + tau (serial; m <= 160)
    if (t == 0) {
        float c = 0.f;
        int kmax = 1;
        float csk = srt[0];
        for (int jj = 0; jj < m; ++jj) {
            c += srt[jj];
            if (1.0f + (float)(jj + 1) * srt[jj] > c) { kmax = jj + 1; csk = c; }
        }
        s_tau = (csk - 1.0f) / (float)kmax;
        s_thresh = 0.f;
    }
    __syncthreads();
    float tau = s_tau;

    // phase 3: K-th largest among UNIQUE cols (dups collapse in dense adj)
    for (int i = t; i < m; i += 64) {
        if (dupf[i]) continue;
        float zi = zs[i];
        int rank = 0;
        for (int jj = 0; jj < m; ++jj) {
            if (dupf[jj] || jj == i) continue;
            float zj = zs[jj];
            rank += (zj > zi) || (zj == zi && jj < i);
        }
        if (rank == KTOP - 1) {       // at most one element (strict total order)
            float s = zi - tau;
            s_thresh = s > 0.f ? s : 0.f;
        }
    }
    __syncthreads();
    float thresh = s_thresh;

    // phase 4: write only the kept entries (dup writes identical — benign)
    float* row = adj + (size_t)r * N_;
    for (int i = t; i < m; i += 64) {
        float s = zs[i] - tau;
        if (s > 0.f && s >= thresh) row[cols[i]] = s;
    }
}

extern "C" void kernel_launch(void* const* d_in, const int* in_sizes, int n_in,
                              void* d_out, int out_size, void* d_ws, size_t ws_size,
                              hipStream_t stream) {
    const float* x  = (const float*)d_in[0];
    const int*   ei = (const int*)d_in[1];
    const float* W1 = (const float*)d_in[2];
    const float* b1 = (const float*)d_in[3];
    const float* We = (const float*)d_in[4];
    const float* be = (const float*)d_in[5];

    float* h_out   = (float*)d_out;                 // (N, NHID)
    float* adj_out = h_out + (size_t)N_ * NHID_;    // (N, N)

    float* a    = (float*)d_ws;                     // N
    float* b    = a + N_;                           // N
    int*   cnt  = (int*)(b + N_);                   // N
    int*   ecol = cnt + N_;                         // N*CAP

    k_gemm_ab<<<N_ / 8, 256, 0, stream>>>(x, W1, b1, We, h_out, a, b, cnt, adj_out);
    k_scatter<<<E_ / 256, 256, 0, stream>>>(ei, cnt, ecol, adj_out);
    k_rows   <<<N_, 64, 0, stream>>>(cnt, ecol, a, b, be, adj_out);
}

// Round 5
// 392.525 us; speedup vs baseline: 1.0479x; 1.0479x over previous
//
#include <hip/hip_runtime.h>

#define N_    8192
#define FIN_  256
#define NHID_ 128
#define E_    524288
#define KTOP  32
#define CAP   160   // bucket capacity per row; Binomial(E,1/N): mean 64, sigma 8 -> 160 = +12 sigma

// ---- fused: h = relu(x @ W1 + b1); a = h.We1; b = h.We2; cnt = 0 ----
// block = 8 rows x 128 cols; thread (row = t>>5, jg = t&31) computes 4 cols.
__global__ __launch_bounds__(256) void k_gemm_ab(const float* __restrict__ x,
                                                 const float* __restrict__ W1,
                                                 const float* __restrict__ b1,
                                                 const float* __restrict__ We,
                                                 float* __restrict__ h,
                                                 float* __restrict__ a,
                                                 float* __restrict__ b,
                                                 int* __restrict__ cnt) {
    __shared__ float xs[8][FIN_];
    int t = threadIdx.x;
    int row0 = blockIdx.x * 8;
    const float4* xg = (const float4*)(x + (size_t)row0 * FIN_);
    float4* xs4 = (float4*)&xs[0][0];
    xs4[t]       = xg[t];          // 8*256 floats = 512 float4, 2 per thread
    xs4[t + 256] = xg[t + 256];
    if (t < 8) cnt[row0 + t] = 0;  // fused cnt zeroing (k_scatter is stream-ordered after)
    __syncthreads();
    int row = t >> 5;
    int jg  = t & 31;
    const float* wp = W1 + jg * 4;
    float4 acc = *(const float4*)(b1 + jg * 4);
    const float* xr = xs[row];
#pragma unroll 8
    for (int k = 0; k < FIN_; ++k) {
        float4 w = *(const float4*)(wp + (size_t)k * NHID_);
        float xv = xr[k];
        acc.x = fmaf(xv, w.x, acc.x);
        acc.y = fmaf(xv, w.y, acc.y);
        acc.z = fmaf(xv, w.z, acc.z);
        acc.w = fmaf(xv, w.w, acc.w);
    }
    acc.x = fmaxf(acc.x, 0.f);
    acc.y = fmaxf(acc.y, 0.f);
    acc.z = fmaxf(acc.z, 0.f);
    acc.w = fmaxf(acc.w, 0.f);
    *(float4*)(h + (size_t)(row0 + row) * NHID_ + jg * 4) = acc;

    // epilogue: per-node scalars from the relu'd registers (32-lane tree per row)
    float4 we1 = *(const float4*)(We + jg * 4);
    float4 we2 = *(const float4*)(We + NHID_ + jg * 4);
    float p = acc.x * we1.x + acc.y * we1.y + acc.z * we1.z + acc.w * we1.w;
    float q = acc.x * we2.x + acc.y * we2.y + acc.z * we2.z + acc.w * we2.w;
#pragma unroll
    for (int o = 16; o > 0; o >>= 1) {
        p += __shfl_down(p, o, 32);
        q += __shfl_down(q, o, 32);
    }
    if (jg == 0) { a[row0 + row] = p; b[row0 + row] = q; }
}

// ---- bucket edges by row (fixed-capacity, atomic append) ----
__global__ __launch_bounds__(256) void k_scatter(const int* __restrict__ ei,
                                                 int* __restrict__ cnt,
                                                 int* __restrict__ ecol) {
    int e = blockIdx.x * 256 + threadIdx.x;
    int r = ei[e];
    int c = ei[E_ + e];
    int pos = atomicAdd(&cnt[r], 1);
    if (pos < CAP) ecol[r * CAP + pos] = c;
}

// ---- per-row sparsemax + topK threshold + dense row write ----
// One WAVE per row, 4 rows per block; all phases wave-local (no barrier convoy).
// Single __syncthreads only to drain vmcnt (zero stores) before the scatter stores.
__global__ __launch_bounds__(256) void k_rows(const int* __restrict__ cnt,
                                              const int* __restrict__ ecol,
                                              const float* __restrict__ a,
                                              const float* __restrict__ b,
                                              const float* __restrict__ be,
                                              float* __restrict__ adj) {
    __shared__ float zs[4][CAP];
    __shared__ int   cols[4][CAP];
    __shared__ float srt[4][CAP];
    __shared__ int   dupf[4][CAP];

    int t = threadIdx.x;
    int wave = t >> 6, lane = t & 63;
    int r = blockIdx.x * 4 + wave;
    int m = cnt[r];
    if (m > CAP) m = CAP;

    // zero this wave's dense output row: 2048 float4 / 64 lanes = 32 each, coalesced
    float* row = adj + (size_t)r * N_;
    float4* row4 = (float4*)row;
    float4 z4 = make_float4(0.f, 0.f, 0.f, 0.f);
#pragma unroll
    for (int i = 0; i < 32; ++i) row4[lane + 64 * i] = z4;

    float tau = 0.f, thresh = 0.f;
    if (m > 0) {
        // load bucket; z = a[r] + b[c] + be  (b[] is 32 KB, L2-resident gather)
        float ab = a[r] + be[0];
        for (int i = lane; i < m; i += 64) {
            int c = ecol[r * CAP + i];
            cols[wave][i] = c;
            zs[wave][i] = ab + b[c];
        }
        // phase 1: descending rank (ties by bucket index) + duplicate-col flags
        for (int i = lane; i < m; i += 64) {
            float zi = zs[wave][i];
            int ci = cols[wave][i];
            int rank = 0;
            for (int jj = 0; jj < m; ++jj) {
                float zj = zs[wave][jj];
                rank += (zj > zi) || (zj == zi && jj < i);
            }
            int dup = 0;
            for (int jj = 0; jj < i; ++jj)
                if (cols[wave][jj] == ci) { dup = 1; break; }
            srt[wave][rank] = zi;
            dupf[wave][i] = dup;
        }
        // phase 2: sparsemax support size + tau (serial on lane 0; m <= 160)
        if (lane == 0) {
            float c = 0.f;
            int kmax = 1;
            float csk = srt[wave][0];
            for (int jj = 0; jj < m; ++jj) {
                c += srt[wave][jj];
                if (1.0f + (float)(jj + 1) * srt[wave][jj] > c) { kmax = jj + 1; csk = c; }
            }
            tau = (csk - 1.0f) / (float)kmax;
        }
        tau = __shfl(tau, 0);

        // phase 3: K-th largest among UNIQUE cols (dups collapse in dense adj)
        float cand = 0.f;
        for (int i = lane; i < m; i += 64) {
            if (dupf[wave][i]) continue;
            float zi = zs[wave][i];
            int rank = 0;
            for (int jj = 0; jj < m; ++jj) {
                if (dupf[wave][jj] || jj == i) continue;
                float zj = zs[wave][jj];
                rank += (zj > zi) || (zj == zi && jj < i);
            }
            if (rank == KTOP - 1) {       // at most one lane-slot (strict total order)
                float s = zi - tau;
                cand = s > 0.f ? s : 0.f;
            }
        }
#pragma unroll
        for (int o = 32; o > 0; o >>= 1) cand = fmaxf(cand, __shfl_down(cand, o));
        thresh = __shfl(cand, 0);
    }

    __syncthreads();   // drains vmcnt: zero stores committed before scatter stores

    if (m > 0) {
        // phase 4: scatter kept scores over the zeros (dup writes identical — benign)
        for (int i = lane; i < m; i += 64) {
            float s = zs[wave][i] - tau;
            if (s > 0.f && s >= thresh) row[cols[wave][i]] = s;
        }
    }
}

extern "C" void kernel_launch(void* const* d_in, const int* in_sizes, int n_in,
                              void* d_out, int out_size, void* d_ws, size_t ws_size,
                              hipStream_t stream) {
    const float* x  = (const float*)d_in[0];
    const int*   ei = (const int*)d_in[1];
    const float* W1 = (const float*)d_in[2];
    const float* b1 = (const float*)d_in[3];
    const float* We = (const float*)d_in[4];
    const float* be = (const float*)d_in[5];

    float* h_out   = (float*)d_out;                 // (N, NHID)
    float* adj_out = h_out + (size_t)N_ * NHID_;    // (N, N)

    float* a    = (float*)d_ws;                     // N
    float* b    = a + N_;                           // N
    int*   cnt  = (int*)(b + N_);                   // N
    int*   ecol = cnt + N_;                         // N*CAP

    k_gemm_ab<<<N_ / 8, 256, 0, stream>>>(x, W1, b1, We, h_out, a, b, cnt);
    k_scatter<<<E_ / 256, 256, 0, stream>>>(ei, cnt, ecol);
    k_rows   <<<N_ / 4, 256, 0, stream>>>(cnt, ecol, a, b, be, adj_out);
}

// Round 6
// 375.532 us; speedup vs baseline: 1.0953x; 1.0453x over previous
//
#include <hip/hip_runtime.h>

#define N_    8192
#define FIN_  256
#define NHID_ 128
#define E_    524288
#define KTOP  32
#define CAP   160   // bucket capacity per row; Binomial(E,1/N): mean 64, sigma 8 -> 160 = +12 sigma

// ---- fused: edge scatter + h = relu(x @ W1 + b1) + a,b epilogue ----
// 512 blocks. Each block: scatters 1024 edges (issues first, hides under compute),
// then computes 16 rows x 128 cols of h. Thread = 2 rows x 4 cols -> 8 FMA per
// W1 float4 (halves L1 traffic vs 1x4); 2 blocks/CU.
__global__ __launch_bounds__(256) void k_fused(const float* __restrict__ x,
                                               const int* __restrict__ ei,
                                               const float* __restrict__ W1,
                                               const float* __restrict__ b1,
                                               const float* __restrict__ We,
                                               float* __restrict__ h,
                                               float* __restrict__ a,
                                               float* __restrict__ b,
                                               int* __restrict__ cnt,
                                               int* __restrict__ ecol) {
    __shared__ float xs[16][FIN_];
    int t = threadIdx.x;
    int blk = blockIdx.x;

    // ---- scatter slice: 1024 edges, int4-coalesced (cnt pre-zeroed by memset) ----
    {
        int4 r4 = ((const int4*)ei)[blk * 256 + t];
        int4 c4 = ((const int4*)(ei + E_))[blk * 256 + t];
        int p;
        p = atomicAdd(&cnt[r4.x], 1); if (p < CAP) ecol[r4.x * CAP + p] = c4.x;
        p = atomicAdd(&cnt[r4.y], 1); if (p < CAP) ecol[r4.y * CAP + p] = c4.y;
        p = atomicAdd(&cnt[r4.z], 1); if (p < CAP) ecol[r4.z * CAP + p] = c4.z;
        p = atomicAdd(&cnt[r4.w], 1); if (p < CAP) ecol[r4.w * CAP + p] = c4.w;
    }

    // ---- stage 16 rows of x into LDS: 1024 float4, 4 per thread ----
    int row0 = blk * 16;
    const float4* xg = (const float4*)(x + (size_t)row0 * FIN_);
    float4* xs4 = (float4*)&xs[0][0];
#pragma unroll
    for (int i = 0; i < 4; ++i) xs4[t + 256 * i] = xg[t + 256 * i];
    __syncthreads();

    int rg = t >> 5;           // row-group: rows 2*rg, 2*rg+1
    int jg = t & 31;           // col-group: cols 4*jg .. 4*jg+3
    int r0 = 2 * rg, r1 = 2 * rg + 1;
    const float* wp = W1 + jg * 4;
    float4 bb = *(const float4*)(b1 + jg * 4);
    float4 acc0 = bb, acc1 = bb;
    const float* xr0 = xs[r0];
    const float* xr1 = xs[r1];
#pragma unroll 8
    for (int k = 0; k < FIN_; ++k) {
        float4 w = *(const float4*)(wp + (size_t)k * NHID_);
        float x0 = xr0[k], x1 = xr1[k];
        acc0.x = fmaf(x0, w.x, acc0.x);
        acc0.y = fmaf(x0, w.y, acc0.y);
        acc0.z = fmaf(x0, w.z, acc0.z);
        acc0.w = fmaf(x0, w.w, acc0.w);
        acc1.x = fmaf(x1, w.x, acc1.x);
        acc1.y = fmaf(x1, w.y, acc1.y);
        acc1.z = fmaf(x1, w.z, acc1.z);
        acc1.w = fmaf(x1, w.w, acc1.w);
    }
    acc0.x = fmaxf(acc0.x, 0.f); acc0.y = fmaxf(acc0.y, 0.f);
    acc0.z = fmaxf(acc0.z, 0.f); acc0.w = fmaxf(acc0.w, 0.f);
    acc1.x = fmaxf(acc1.x, 0.f); acc1.y = fmaxf(acc1.y, 0.f);
    acc1.z = fmaxf(acc1.z, 0.f); acc1.w = fmaxf(acc1.w, 0.f);
    *(float4*)(h + (size_t)(row0 + r0) * NHID_ + jg * 4) = acc0;
    *(float4*)(h + (size_t)(row0 + r1) * NHID_ + jg * 4) = acc1;

    // ---- epilogue: a,b per-node scalars (32-lane tree per row) ----
    float4 we1 = *(const float4*)(We + jg * 4);
    float4 we2 = *(const float4*)(We + NHID_ + jg * 4);
    float p0 = acc0.x * we1.x + acc0.y * we1.y + acc0.z * we1.z + acc0.w * we1.w;
    float q0 = acc0.x * we2.x + acc0.y * we2.y + acc0.z * we2.z + acc0.w * we2.w;
    float p1 = acc1.x * we1.x + acc1.y * we1.y + acc1.z * we1.z + acc1.w * we1.w;
    float q1 = acc1.x * we2.x + acc1.y * we2.y + acc1.z * we2.z + acc1.w * we2.w;
#pragma unroll
    for (int o = 16; o > 0; o >>= 1) {
        p0 += __shfl_down(p0, o, 32);
        q0 += __shfl_down(q0, o, 32);
        p1 += __shfl_down(p1, o, 32);
        q1 += __shfl_down(q1, o, 32);
    }
    if (jg == 0) {
        a[row0 + r0] = p0; b[row0 + r0] = q0;
        a[row0 + r1] = p1; b[row0 + r1] = q1;
    }
}

// ---- per-row sparsemax + topK threshold + dense row write (R3 best-measured) ----
__global__ __launch_bounds__(256) void k_rows(const int* __restrict__ cnt,
                                              const int* __restrict__ ecol,
                                              const float* __restrict__ a,
                                              const float* __restrict__ b,
                                              const float* __restrict__ be,
                                              float* __restrict__ adj) {
    __shared__ float zs[CAP];
    __shared__ int   cols[CAP];
    __shared__ float srt[CAP];
    __shared__ unsigned char dupf[CAP];
    __shared__ float s_tau, s_thresh;

    int r = blockIdx.x;
    int t = threadIdx.x;
    int m = cnt[r];
    if (m > CAP) m = CAP;

    // zero the dense output row (issues before compute; overlaps across blocks)
    float* row = adj + (size_t)r * N_;
    float4* row4 = (float4*)row;
    float4 z4 = make_float4(0.f, 0.f, 0.f, 0.f);
#pragma unroll
    for (int i = 0; i < 8; ++i) row4[t + 256 * i] = z4;

    // load bucket; z = a[r] + b[c] + be  (b[] is 32 KB, L2-resident gather)
    float ab = a[r] + be[0];
    for (int i = t; i < m; i += 256) {
        int c = ecol[r * CAP + i];
        cols[i] = c;
        zs[i] = ab + b[c];
    }
    __syncthreads();                  // drains vmcnt: zeros committed, LDS visible
    if (m == 0) return;               // uniform branch

    // phase 1: descending rank (ties by bucket index) + duplicate-col flags
    for (int i = t; i < m; i += 256) {
        float zi = zs[i];
        int ci = cols[i];
        int rank = 0;
        for (int jj = 0; jj < m; ++jj) {
            float zj = zs[jj];
            rank += (zj > zi) || (zj == zi && jj < i);
        }
        bool dup = false;
        for (int jj = 0; jj < i; ++jj)
            if (cols[jj] == ci) { dup = true; break; }
        srt[rank] = zi;
        dupf[i] = dup ? 1 : 0;
    }
    __syncthreads();

    // phase 2: sparsemax support size + tau (serial; m <= 160)
    if (t == 0) {
        float c = 0.f;
        int kmax = 1;
        float csk = srt[0];
        for (int jj = 0; jj < m; ++jj) {
            c += srt[jj];
            if (1.0f + (float)(jj + 1) * srt[jj] > c) { kmax = jj + 1; csk = c; }
        }
        s_tau = (csk - 1.0f) / (float)kmax;
        s_thresh = 0.f;
    }
    __syncthreads();
    float tau = s_tau;

    // phase 3: K-th largest among UNIQUE cols (dups collapse in dense adj)
    for (int i = t; i < m; i += 256) {
        if (dupf[i]) continue;
        float zi = zs[i];
        int rank = 0;
        for (int jj = 0; jj < m; ++jj) {
            if (dupf[jj] || jj == i) continue;
            float zj = zs[jj];
            rank += (zj > zi) || (zj == zi && jj < i);
        }
        if (rank == KTOP - 1) {       // at most one element (strict total order)
            float s = zi - tau;
            s_thresh = s > 0.f ? s : 0.f;
        }
    }
    __syncthreads();
    float thresh = s_thresh;

    // phase 4: scatter kept scores over the zeros (dup writes identical — benign)
    for (int i = t; i < m; i += 256) {
        float s = zs[i] - tau;
        if (s > 0.f && s >= thresh) row[cols[i]] = s;
    }
}

extern "C" void kernel_launch(void* const* d_in, const int* in_sizes, int n_in,
                              void* d_out, int out_size, void* d_ws, size_t ws_size,
                              hipStream_t stream) {
    const float* x  = (const float*)d_in[0];
    const int*   ei = (const int*)d_in[1];
    const float* W1 = (const float*)d_in[2];
    const float* b1 = (const float*)d_in[3];
    const float* We = (const float*)d_in[4];
    const float* be = (const float*)d_in[5];

    float* h_out   = (float*)d_out;                 // (N, NHID)
    float* adj_out = h_out + (size_t)N_ * NHID_;    // (N, N)

    float* a    = (float*)d_ws;                     // N
    float* b    = a + N_;                           // N
    int*   cnt  = (int*)(b + N_);                   // N
    int*   ecol = cnt + N_;                         // N*CAP

    hipMemsetAsync(cnt, 0, N_ * sizeof(int), stream);
    k_fused<<<512, 256, 0, stream>>>(x, ei, W1, b1, We, h_out, a, b, cnt, ecol);
    k_rows <<<N_, 256, 0, stream>>>(cnt, ecol, a, b, be, adj_out);
}

// Round 7
// 371.110 us; speedup vs baseline: 1.1084x; 1.0119x over previous
//
#include <hip/hip_runtime.h>

#define N_    8192
#define FIN_  256
#define NHID_ 128
#define E_    524288
#define KTOP  32
#define CAP   160    // bucket capacity per row; Binomial(E,1/N): mean 64, sigma 8 -> 160 = +12 sigma
#define HASHSZ 512   // LDS hash slots (kept entries <= 160 -> load factor <= 31%)

typedef unsigned short ushort_t;

// ---- fused: edge scatter + h = relu(x @ W1 + b1) + a,b epilogue ----
__global__ __launch_bounds__(256) void k_fused(const float* __restrict__ x,
                                               const int* __restrict__ ei,
                                               const float* __restrict__ W1,
                                               const float* __restrict__ b1,
                                               const float* __restrict__ We,
                                               float* __restrict__ h,
                                               float* __restrict__ a,
                                               float* __restrict__ b,
                                               int* __restrict__ cnt,
                                               ushort_t* __restrict__ ecol) {
    __shared__ float xs[16][FIN_];
    int t = threadIdx.x;
    int blk = blockIdx.x;

    // ---- scatter slice: 1024 edges, int4-coalesced (cnt pre-zeroed by memset) ----
    {
        int4 r4 = ((const int4*)ei)[blk * 256 + t];
        int4 c4 = ((const int4*)(ei + E_))[blk * 256 + t];
        int p;
        p = atomicAdd(&cnt[r4.x], 1); if (p < CAP) ecol[r4.x * CAP + p] = (ushort_t)c4.x;
        p = atomicAdd(&cnt[r4.y], 1); if (p < CAP) ecol[r4.y * CAP + p] = (ushort_t)c4.y;
        p = atomicAdd(&cnt[r4.z], 1); if (p < CAP) ecol[r4.z * CAP + p] = (ushort_t)c4.z;
        p = atomicAdd(&cnt[r4.w], 1); if (p < CAP) ecol[r4.w * CAP + p] = (ushort_t)c4.w;
    }

    // ---- stage 16 rows of x into LDS: 1024 float4, 4 per thread ----
    int row0 = blk * 16;
    const float4* xg = (const float4*)(x + (size_t)row0 * FIN_);
    float4* xs4 = (float4*)&xs[0][0];
#pragma unroll
    for (int i = 0; i < 4; ++i) xs4[t + 256 * i] = xg[t + 256 * i];
    __syncthreads();

    int rg = t >> 5;           // row-group: rows 2*rg, 2*rg+1
    int jg = t & 31;           // col-group: cols 4*jg .. 4*jg+3
    int r0 = 2 * rg, r1 = 2 * rg + 1;
    const float* wp = W1 + jg * 4;
    float4 bb = *(const float4*)(b1 + jg * 4);
    float4 acc0 = bb, acc1 = bb;
    const float* xr0 = xs[r0];
    const float* xr1 = xs[r1];
#pragma unroll 8
    for (int k = 0; k < FIN_; ++k) {
        float4 w = *(const float4*)(wp + (size_t)k * NHID_);
        float x0 = xr0[k], x1 = xr1[k];
        acc0.x = fmaf(x0, w.x, acc0.x);
        acc0.y = fmaf(x0, w.y, acc0.y);
        acc0.z = fmaf(x0, w.z, acc0.z);
        acc0.w = fmaf(x0, w.w, acc0.w);
        acc1.x = fmaf(x1, w.x, acc1.x);
        acc1.y = fmaf(x1, w.y, acc1.y);
        acc1.z = fmaf(x1, w.z, acc1.z);
        acc1.w = fmaf(x1, w.w, acc1.w);
    }
    acc0.x = fmaxf(acc0.x, 0.f); acc0.y = fmaxf(acc0.y, 0.f);
    acc0.z = fmaxf(acc0.z, 0.f); acc0.w = fmaxf(acc0.w, 0.f);
    acc1.x = fmaxf(acc1.x, 0.f); acc1.y = fmaxf(acc1.y, 0.f);
    acc1.z = fmaxf(acc1.z, 0.f); acc1.w = fmaxf(acc1.w, 0.f);
    *(float4*)(h + (size_t)(row0 + r0) * NHID_ + jg * 4) = acc0;
    *(float4*)(h + (size_t)(row0 + r1) * NHID_ + jg * 4) = acc1;

    // ---- epilogue: a,b per-node scalars (32-lane tree per row) ----
    float4 we1 = *(const float4*)(We + jg * 4);
    float4 we2 = *(const float4*)(We + NHID_ + jg * 4);
    float p0 = acc0.x * we1.x + acc0.y * we1.y + acc0.z * we1.z + acc0.w * we1.w;
    float q0 = acc0.x * we2.x + acc0.y * we2.y + acc0.z * we2.z + acc0.w * we2.w;
    float p1 = acc1.x * we1.x + acc1.y * we1.y + acc1.z * we1.z + acc1.w * we1.w;
    float q1 = acc1.x * we2.x + acc1.y * we2.y + acc1.z * we2.z + acc1.w * we2.w;
#pragma unroll
    for (int o = 16; o > 0; o >>= 1) {
        p0 += __shfl_down(p0, o, 32);
        q0 += __shfl_down(q0, o, 32);
        p1 += __shfl_down(p1, o, 32);
        q1 += __shfl_down(q1, o, 32);
    }
    if (jg == 0) {
        a[row0 + r0] = p0; b[row0 + r0] = q0;
        a[row0 + r1] = p1; b[row0 + r1] = q1;
    }
}

// ---- per-row sparsemax + topK; compute FIRST, then one fill-like streaming pass ----
__global__ __launch_bounds__(256) void k_rows(const int* __restrict__ cnt,
                                              const ushort_t* __restrict__ ecol,
                                              const float* __restrict__ a,
                                              const float* __restrict__ b,
                                              const float* __restrict__ be,
                                              float* __restrict__ adj) {
    __shared__ float zs[CAP];
    __shared__ int   cols[CAP];
    __shared__ float srt[CAP];
    __shared__ unsigned char dupf[CAP];
    __shared__ unsigned int bitmap[N_ / 32];   // 256 words, 1 KB
    __shared__ int   hcol[HASHSZ];             // 2 KB
    __shared__ float hval[HASHSZ];             // 2 KB
    __shared__ float s_tau, s_thresh;

    int r = blockIdx.x;
    int t = threadIdx.x;
    int m = cnt[r];
    if (m > CAP) m = CAP;

    // init bitmap + hash
    bitmap[t] = 0u;
    hcol[t] = -1;
    hcol[t + 256] = -1;

    // load bucket; z = a[r] + b[c] + be  (b[] is 32 KB, L2-resident gather)
    float ab = a[r] + be[0];
    for (int i = t; i < m; i += 256) {
        int c = (int)ecol[r * CAP + i];
        cols[i] = c;
        zs[i] = ab + b[c];
    }
    __syncthreads();

    if (m > 0) {                      // uniform per block
        // phase 1: descending rank (ties by bucket index) + duplicate-col flags
        for (int i = t; i < m; i += 256) {
            float zi = zs[i];
            int ci = cols[i];
            int rank = 0;
            for (int jj = 0; jj < m; ++jj) {
                float zj = zs[jj];
                rank += (zj > zi) || (zj == zi && jj < i);
            }
            bool dup = false;
            for (int jj = 0; jj < i; ++jj)
                if (cols[jj] == ci) { dup = true; break; }
            srt[rank] = zi;
            dupf[i] = dup ? 1 : 0;
        }
        __syncthreads();

        // phase 2: sparsemax support size + tau (serial; m <= 160)
        if (t == 0) {
            float c = 0.f;
            int kmax = 1;
            float csk = srt[0];
            for (int jj = 0; jj < m; ++jj) {
                c += srt[jj];
                if (1.0f + (float)(jj + 1) * srt[jj] > c) { kmax = jj + 1; csk = c; }
            }
            s_tau = (csk - 1.0f) / (float)kmax;
            s_thresh = 0.f;
        }
        __syncthreads();
        float tau = s_tau;

        // phase 3: K-th largest among UNIQUE cols (dups collapse in dense adj)
        for (int i = t; i < m; i += 256) {
            if (dupf[i]) continue;
            float zi = zs[i];
            int rank = 0;
            for (int jj = 0; jj < m; ++jj) {
                if (dupf[jj] || jj == i) continue;
                float zj = zs[jj];
                rank += (zj > zi) || (zj == zi && jj < i);
            }
            if (rank == KTOP - 1) {   // at most one element (strict total order)
                float s = zi - tau;
                s_thresh = s > 0.f ? s : 0.f;
            }
        }
        __syncthreads();
        float thresh = s_thresh;

        // phase 4: insert kept entries into bitmap + hash (unique cols only)
        for (int i = t; i < m; i += 256) {
            if (dupf[i]) continue;
            float s = zs[i] - tau;
            if (s > 0.f && s >= thresh) {
                int c = cols[i];
                atomicOr(&bitmap[c >> 5], 1u << (c & 31));
                int slot = c & (HASHSZ - 1);
                while (atomicCAS(&hcol[slot], -1, c) != -1)
                    slot = (slot + 1) & (HASHSZ - 1);
                hval[slot] = s;
            }
        }
    }
    __syncthreads();

    // streaming pass: write the full 32 KB row once (mostly zeros)
    float4* row4 = (float4*)(adj + (size_t)r * N_);
#pragma unroll
    for (int k2 = 0; k2 < 8; ++k2) {
        int idx = t + 256 * k2;                 // float4 index; cols 4*idx..4*idx+3
        unsigned int word = bitmap[idx >> 3];
        unsigned int nib = (word >> ((idx & 7) * 4)) & 0xFu;
        float4 v = make_float4(0.f, 0.f, 0.f, 0.f);
        if (nib) {
            int cbase = idx * 4;
#pragma unroll
            for (int bbit = 0; bbit < 4; ++bbit) {
                if (nib & (1u << bbit)) {
                    int c = cbase + bbit;
                    int slot = c & (HASHSZ - 1);
                    while (hcol[slot] != c) slot = (slot + 1) & (HASHSZ - 1);
                    float val = hval[slot];
                    if (bbit == 0) v.x = val;
                    else if (bbit == 1) v.y = val;
                    else if (bbit == 2) v.z = val;
                    else v.w = val;
                }
            }
        }
        row4[idx] = v;
    }
}

extern "C" void kernel_launch(void* const* d_in, const int* in_sizes, int n_in,
                              void* d_out, int out_size, void* d_ws, size_t ws_size,
                              hipStream_t stream) {
    const float* x  = (const float*)d_in[0];
    const int*   ei = (const int*)d_in[1];
    const float* W1 = (const float*)d_in[2];
    const float* b1 = (const float*)d_in[3];
    const float* We = (const float*)d_in[4];
    const float* be = (const float*)d_in[5];

    float* h_out   = (float*)d_out;                 // (N, NHID)
    float* adj_out = h_out + (size_t)N_ * NHID_;    // (N, N)

    float*    a    = (float*)d_ws;                  // N
    float*    b    = a + N_;                        // N
    int*      cnt  = (int*)(b + N_);                // N
    ushort_t* ecol = (ushort_t*)(cnt + N_);         // N*CAP ushort

    hipMemsetAsync(cnt, 0, N_ * sizeof(int), stream);
    k_fused<<<512, 256, 0, stream>>>(x, ei, W1, b1, We, h_out, a, b, cnt, ecol);
    k_rows <<<N_, 256, 0, stream>>>(cnt, ecol, a, b, be, adj_out);
}